// Round 7
// baseline (197.198 us; speedup 1.0000x reference)
//
#include <hip/hip_runtime.h>
#include <hip/hip_bf16.h>

// AttnPredictor round 7: 2 dispatches, occupancy-tuned.
//  kA (1248 blocks, range-specialized):
//   [0,64)     P1: w = softmax_d(z*(a@Wqk + bqk)/sqrt192) (bk·q cancels),
//              attn_weights, ae = a@Wav + bav
//   [64,224)   U[h,d,k] = Wfv[d,:]·W1[h,0:128,k] ; dt==4: c0 = bfv·W1[h,0:128]+b1
//   [224,1248) M_T[h][k2][k1] = (W2[h]@W1o[h])^T bf16 (32 blocks/h, 8 rows each);
//              c1 = b2@W1o + b1o
//  kB (2048 blocks = 32 h x 64 btiles of 8, <=64 VGPR for 8 blocks/CU):
//   G[bi][k] = ae·W1[h,128:192,k] + c0    (LDS, two 32-reg passes)
//   P[bi][k] = sum_d w_d*relu(z_d*U + G)  (bf16 LDS, rows 8-15 zero-padded)
//   effect   = relu(P@M + c1)·W2o + b2o   via mfma_f32_16x16x32_bf16

typedef __attribute__((ext_vector_type(8))) short bf16x8;
typedef __attribute__((ext_vector_type(4))) short bf16x4;
typedef __attribute__((ext_vector_type(4))) float f32x4;

__device__ __forceinline__ short f2bf(float x) {
  unsigned u = __float_as_uint(x);
  u += 0x7fffu + ((u >> 16) & 1u);          // round-to-nearest-even
  return (short)(u >> 16);
}

__global__ __launch_bounds__(256) void kA_prep(
    const float* __restrict__ feat, const float* __restrict__ act,
    const float* __restrict__ Wq, const float* __restrict__ bq,
    const float* __restrict__ Wk,
    const float* __restrict__ Wav, const float* __restrict__ bav,
    const float* __restrict__ Wfv, const float* __restrict__ bfv,
    const float* __restrict__ W1, const float* __restrict__ b1,
    const float* __restrict__ W2, const float* __restrict__ b2,
    const float* __restrict__ W1o, const float* __restrict__ b1o,
    float* __restrict__ ws_w, float* __restrict__ ws_ae,
    float* __restrict__ ws_U, float* __restrict__ ws_c0,
    unsigned short* __restrict__ ws_Mbf, float* __restrict__ ws_c1,
    float* __restrict__ out_aw) {
  __shared__ float sh[7152];                // 28.6 KB -> 5 blocks/CU
  const int bx = blockIdx.x;
  const int t = threadIdx.x;

  if (bx < 64) {
    // ---------------- P1: softmax weights + attn_weights + ae (8 b per block)
    const int b0 = bx * 8;
    float* sWk = sh;                        // [192 c][32 d] transposed
    float* sA  = sh + 6144;                 // act [8][18]
    float* sQk = sh + 6288;                 // [19 j][32 d] (row 18 = bq row)
    float* sW  = sh + 6896;                 // [8][32]
#pragma unroll
    for (int i = 0; i < 24; ++i) {
      const int idx = i * 256 + t;          // idx = d*192 + c
      sWk[(idx % 192) * 32 + (idx / 192)] = Wk[idx];
    }
    if (t < 144) sA[t] = act[b0 * 18 + t];
    __syncthreads();
    for (int o = t; o < 608; o += 256) {    // Wqk[j][d]; j==18 -> bqk
      const int j = o >> 5, d = o & 31;
      const float* arow = (j < 18) ? (Wq + j * 192) : bq;
      float acc = 0.f;
      for (int c = 0; c < 192; ++c) acc += arow[c] * sWk[c * 32 + d];
      sQk[o] = acc;
    }
    __syncthreads();
    {
      const int bi = t >> 5, d = t & 31;
      float dot = sQk[18 * 32 + d];
#pragma unroll
      for (int j = 0; j < 18; ++j) dot += sA[bi * 18 + j] * sQk[j * 32 + d];
      const float z = feat[b0 * 32 + t];
      float sc = z * dot * 0.07216878364870322f;   // 1/sqrt(192)
      float mx = sc;
#pragma unroll
      for (int off = 16; off >= 1; off >>= 1) mx = fmaxf(mx, __shfl_xor(mx, off, 64));
      const float e = __expf(sc - mx);
      float s = e;
#pragma unroll
      for (int off = 16; off >= 1; off >>= 1) s += __shfl_xor(s, off, 64);
      const float w = e / s;
      ws_w[b0 * 32 + t] = w;
      sW[t] = w;
    }
#pragma unroll
    for (int o = t; o < 512; o += 256) {    // ae = a@Wav + bav
      const int bi = o >> 6, j = o & 63;
      float acc = bav[j];
#pragma unroll
      for (int jj = 0; jj < 18; ++jj) acc += sA[bi * 18 + jj] * Wav[jj * 64 + j];
      ws_ae[b0 * 64 + o] = acc;
    }
    __syncthreads();
#pragma unroll
    for (int i = 0; i < 32; ++i)
      out_aw[b0 * 1024 + i * 256 + t] = sW[(i >> 2) * 32 + (t & 31)];

  } else if (bx < 224) {
    // ---------------- U range: 5 blocks per h (dt<4: 8 d's; dt==4: c0)
    const int r = bx - 64;
    const int h = r / 5, dt = r % 5;
    float* sF = sh;                         // [8][128] Wfv tile (or bfv)
    if (dt < 4) {
#pragma unroll
      for (int i = 0; i < 4; ++i) sF[i * 256 + t] = Wfv[dt * 1024 + i * 256 + t];
    } else {
      if (t < 128) sF[t] = bfv[t];
    }
    __syncthreads();
    if (dt < 4) {
      float acc[8];
#pragma unroll
      for (int dd = 0; dd < 8; ++dd) acc[dd] = 0.f;
      for (int fc = 0; fc < 32; ++fc) {
        float w1v[4];
#pragma unroll
        for (int u = 0; u < 4; ++u) w1v[u] = W1[(h * 192 + fc * 4 + u) * 256 + t];
#pragma unroll
        for (int dd = 0; dd < 8; ++dd) {
          float4 f4 = *(const float4*)(sF + dd * 128 + fc * 4);
          acc[dd] += f4.x * w1v[0] + f4.y * w1v[1] + f4.z * w1v[2] + f4.w * w1v[3];
        }
      }
#pragma unroll
      for (int dd = 0; dd < 8; ++dd)
        ws_U[(h * 32 + dt * 8 + dd) * 256 + t] = acc[dd];
    } else {
      float acc = b1[h * 256 + t];
      for (int fc = 0; fc < 32; ++fc) {
        float w1v[4];
#pragma unroll
        for (int u = 0; u < 4; ++u) w1v[u] = W1[(h * 192 + fc * 4 + u) * 256 + t];
        float4 f4 = *(const float4*)(sF + fc * 4);
        acc += f4.x * w1v[0] + f4.y * w1v[1] + f4.z * w1v[2] + f4.w * w1v[3];
      }
      ws_c0[h * 256 + t] = acc;
    }

  } else {
    // ---------------- M range: 32 blocks/h, 8 k1-rows each
    const int r = bx - 224;
    const int h = r >> 5, kt = r & 31;
    float* s = sh;
#pragma unroll
    for (int i = 0; i < 6; ++i)             // [8 rows][192] W2 tile
      s[i * 256 + t] = W2[h * 49152 + kt * 1536 + i * 256 + t];
    __syncthreads();
    float acc[8];
#pragma unroll
    for (int rr = 0; rr < 8; ++rr) acc[rr] = 0.f;
    float c1acc = 0.f;
    for (int vc = 0; vc < 48; ++vc) {
      float w1o[4], b2v[4];
#pragma unroll
      for (int u = 0; u < 4; ++u) {
        w1o[u] = W1o[(h * 192 + vc * 4 + u) * 256 + t];
        b2v[u] = b2[h * 192 + vc * 4 + u];
      }
      c1acc += b2v[0] * w1o[0] + b2v[1] * w1o[1] + b2v[2] * w1o[2] + b2v[3] * w1o[3];
#pragma unroll
      for (int rr = 0; rr < 8; ++rr) {
        float4 w2 = *(const float4*)(s + rr * 192 + vc * 4);
        acc[rr] += w2.x * w1o[0] + w2.y * w1o[1] + w2.z * w1o[2] + w2.w * w1o[3];
      }
    }
    if (kt == 0) ws_c1[h * 256 + t] = c1acc + b1o[h * 256 + t];
    __syncthreads();
#pragma unroll
    for (int rr = 0; rr < 8; ++rr) s[rr * 260 + t] = acc[rr];
    __syncthreads();
    const int k1l = t & 7, k2g = t >> 3;    // 32 k2-groups
#pragma unroll
    for (int it = 0; it < 8; ++it) {
      const int k2 = it * 32 + k2g;
      ws_Mbf[(h * 256 + k2) * 256 + kt * 8 + k1l] =
          (unsigned short)f2bf(s[k1l * 260 + k2]);
    }
  }
}

// ---------------------------------------------------------------- kB: G (LDS) -> P -> MFMA P@M -> effect
__global__ __launch_bounds__(256, 8) void kB_main(
    const float* __restrict__ feat, const float* __restrict__ ws_w,
    const float* __restrict__ ws_U, const float* __restrict__ W1,
    const float* __restrict__ ws_ae, const float* __restrict__ ws_c0,
    const unsigned short* __restrict__ ws_Mbf, const float* __restrict__ ws_c1,
    const float* __restrict__ W2o, const float* __restrict__ b2o,
    float* __restrict__ out_eff) {
  const int bx = blockIdx.x;
  const int h = (bx & 7) * 4 + ((bx >> 3) & 3);   // XCD swizzle (bijective in bx&31)
  const int bt = bx >> 5;                   // 8 b per block, bt in [0,64)
  const int b0 = bt * 8;
  const int t = threadIdx.x;

  __shared__ __align__(16) char smem[18944];
  short* sP   = (short*)smem;               // [16][264] bf16 (rows 8-15 zero)
  float* sG   = (float*)(smem + 8448);      // [8][260]
  float* sAe  = (float*)(smem + 16768);     // [8][64]
  float* sRed = (float*)(smem + 18816);     // [8][4]

  // ---- zero pad rows 8-15 of sP (1056 dwords)
  {
    int* zp = (int*)(sP + 8 * 264);
    for (int i = t; i < 1056; i += 256) zp[i] = 0;
  }

  // ---- G in LDS: G[bi][k=t] = c0[k] + ae[bi]·W1[h,128:192,k], two 32-reg passes
  {
#pragma unroll
    for (int i = 0; i < 2; ++i) sAe[i * 256 + t] = ws_ae[b0 * 64 + i * 256 + t];
    const float c0v = ws_c0[h * 256 + t];
    float w1r[32];
#pragma unroll
    for (int j = 0; j < 32; ++j) w1r[j] = W1[(h * 192 + 128 + j) * 256 + t];
    __syncthreads();
#pragma unroll
    for (int bi = 0; bi < 8; ++bi) {
      float acc = c0v;
#pragma unroll
      for (int jc = 0; jc < 8; ++jc) {
        float4 a4 = *(const float4*)(sAe + bi * 64 + jc * 4);
        acc += a4.x * w1r[jc * 4 + 0] + a4.y * w1r[jc * 4 + 1]
             + a4.z * w1r[jc * 4 + 2] + a4.w * w1r[jc * 4 + 3];
      }
      sG[bi * 260 + t] = acc;
    }
#pragma unroll
    for (int j = 0; j < 32; ++j) w1r[j] = W1[(h * 192 + 160 + j) * 256 + t];
#pragma unroll
    for (int bi = 0; bi < 8; ++bi) {
      float acc = sG[bi * 260 + t];
#pragma unroll
      for (int jc = 0; jc < 8; ++jc) {
        float4 a4 = *(const float4*)(sAe + bi * 64 + 32 + jc * 4);
        acc += a4.x * w1r[jc * 4 + 0] + a4.y * w1r[jc * 4 + 1]
             + a4.z * w1r[jc * 4 + 2] + a4.w * w1r[jc * 4 + 3];
      }
      sG[bi * 260 + t] = acc;
    }
  }
  __syncthreads();

  // ---- P: thread (bi = t>>5, k in {seg*128 + kg*4 + c}) -> bf16 LDS
  {
    const int bi = t >> 5, kg = t & 31;
    const int b = b0 + bi;
    float g[8], acc[8];
#pragma unroll
    for (int seg = 0; seg < 2; ++seg) {
      float4 g4 = *(const float4*)(sG + bi * 260 + seg * 128 + kg * 4);
      g[seg * 4 + 0] = g4.x; g[seg * 4 + 1] = g4.y;
      g[seg * 4 + 2] = g4.z; g[seg * 4 + 3] = g4.w;
      acc[seg * 4 + 0] = 0.f; acc[seg * 4 + 1] = 0.f;
      acc[seg * 4 + 2] = 0.f; acc[seg * 4 + 3] = 0.f;
    }
    const float* Up = ws_U + h * 8192 + kg * 4;
    for (int dc = 0; dc < 8; ++dc) {
      float4 z4 = *(const float4*)(feat + b * 32 + dc * 4);
      float4 w4 = *(const float4*)(ws_w + b * 32 + dc * 4);
      float zz[4] = {z4.x, z4.y, z4.z, z4.w};
      float wv[4] = {w4.x, w4.y, w4.z, w4.w};
#pragma unroll
      for (int dd = 0; dd < 4; ++dd) {
        const float* Ud = Up + (dc * 4 + dd) * 256;
#pragma unroll
        for (int seg = 0; seg < 2; ++seg) {
          float4 u4 = *(const float4*)(Ud + seg * 128);
          acc[seg * 4 + 0] += wv[dd] * fmaxf(zz[dd] * u4.x + g[seg * 4 + 0], 0.f);
          acc[seg * 4 + 1] += wv[dd] * fmaxf(zz[dd] * u4.y + g[seg * 4 + 1], 0.f);
          acc[seg * 4 + 2] += wv[dd] * fmaxf(zz[dd] * u4.z + g[seg * 4 + 2], 0.f);
          acc[seg * 4 + 3] += wv[dd] * fmaxf(zz[dd] * u4.w + g[seg * 4 + 3], 0.f);
        }
      }
    }
#pragma unroll
    for (int seg = 0; seg < 2; ++seg) {
      bf16x4 p;
#pragma unroll
      for (int j = 0; j < 4; ++j) p[j] = f2bf(acc[seg * 4 + j]);
      *(bf16x4*)(sP + bi * 264 + seg * 128 + kg * 4) = p;
    }
  }
  __syncthreads();

  // ---- MFMA: D[16(8) b][64 k2 per wave] = P @ M ; epilogue
  {
    const int wv = t >> 6;
    const int lane = t & 63;
    const int quad = lane >> 4, l15 = lane & 15;

    f32x4 acc[4];
    const f32x4 zero = {0.f, 0.f, 0.f, 0.f};
#pragma unroll
    for (int nt = 0; nt < 4; ++nt) acc[nt] = zero;

    float c1r[4], w2r[4];
#pragma unroll
    for (int nt = 0; nt < 4; ++nt) {
      const int col = wv * 64 + nt * 16 + l15;
      c1r[nt] = ws_c1[h * 256 + col];
      w2r[nt] = W2o[h * 256 + col];
    }
    const unsigned short* Mp = ws_Mbf + (size_t)(h * 256 + wv * 64) * 256;

#pragma unroll
    for (int kc = 0; kc < 8; ++kc) {
      bf16x8 a0 = *(const bf16x8*)(sP + l15 * 264 + kc * 32 + quad * 8);
      bf16x8 bfr[4];
#pragma unroll
      for (int nt = 0; nt < 4; ++nt)
        bfr[nt] = *(const bf16x8*)(Mp + (nt * 16 + l15) * 256 + kc * 32 + quad * 8);
#pragma unroll
      for (int nt = 0; nt < 4; ++nt)
        acc[nt] = __builtin_amdgcn_mfma_f32_16x16x32_bf16(a0, bfr[nt], acc[nt], 0, 0, 0);
    }
#pragma unroll
    for (int r = 0; r < 4; ++r) {
      const int row = quad * 4 + r;
      float s = fmaxf(acc[0][r] + c1r[0], 0.f) * w2r[0]
              + fmaxf(acc[1][r] + c1r[1], 0.f) * w2r[1]
              + fmaxf(acc[2][r] + c1r[2], 0.f) * w2r[2]
              + fmaxf(acc[3][r] + c1r[3], 0.f) * w2r[3];
      s += __shfl_xor(s, 1, 64);
      s += __shfl_xor(s, 2, 64);
      s += __shfl_xor(s, 4, 64);
      s += __shfl_xor(s, 8, 64);
      if (l15 == 0 && row < 8) sRed[row * 4 + wv] = s;
    }
  }
  __syncthreads();
  if (t < 8) {
    float v = sRed[t * 4] + sRed[t * 4 + 1] + sRed[t * 4 + 2] + sRed[t * 4 + 3] + b2o[h];
    out_eff[(b0 + t) * 32 + h] = v;
  }
}

// ----------------------------------------------------------------
extern "C" void kernel_launch(void* const* d_in, const int* in_sizes, int n_in,
                              void* d_out, int out_size, void* d_ws, size_t ws_size,
                              hipStream_t stream) {
  const float* feat = (const float*)d_in[0];
  const float* act  = (const float*)d_in[1];
  const float* Wq   = (const float*)d_in[2];
  const float* bq   = (const float*)d_in[3];
  const float* Wk   = (const float*)d_in[4];
  // d_in[5] = bk: cancels in softmax
  const float* Wav  = (const float*)d_in[6];
  const float* bav  = (const float*)d_in[7];
  const float* Wfv  = (const float*)d_in[8];
  const float* bfv  = (const float*)d_in[9];
  const float* W1   = (const float*)d_in[10];
  const float* b1   = (const float*)d_in[11];
  const float* W2   = (const float*)d_in[12];
  const float* b2   = (const float*)d_in[13];
  const float* W1o  = (const float*)d_in[14];
  const float* b1o  = (const float*)d_in[15];
  const float* W2o  = (const float*)d_in[16];
  const float* b2o  = (const float*)d_in[17];
  float* out = (float*)d_out;               // [0,16384): effect; rest: attn_weights
  float* ws = (float*)d_ws;

  float* ws_w  = ws;                                        // 16384
  float* ws_ae = ws + 16384;                                // 32768
  float* ws_U  = ws + 49152;                                // 262144
  float* ws_c0 = ws + 311296;                               // 8192
  float* ws_c1 = ws + 319488;                               // 8192
  unsigned short* ws_Mbf = (unsigned short*)(ws + 327680);  // 2097152 shorts

  hipLaunchKernelGGL(kA_prep, dim3(1248), dim3(256), 0, stream,
                     feat, act, Wq, bq, Wk, Wav, bav, Wfv, bfv, W1, b1,
                     W2, b2, W1o, b1o, ws_w, ws_ae, ws_U, ws_c0, ws_Mbf, ws_c1,
                     out + 16384);
  hipLaunchKernelGGL(kB_main, dim3(2048), dim3(256), 0, stream,
                     feat, ws_w, ws_U, W1, ws_ae, ws_c0, ws_Mbf, ws_c1,
                     W2o, b2o, out);
}

// Round 8
// 166.367 us; speedup vs baseline: 1.1853x; 1.1853x over previous
//
#include <hip/hip_runtime.h>
#include <hip/hip_bf16.h>

// AttnPredictor round 8: 2 dispatches. kA = round-6 verbatim. kB redesigned:
// 16 b/block, 1024 blocks, no VGPR cap; P-phase registers reuse each U load
// across 4 batch rows; z/w staged in LDS; 2-pass G; sAe aliased into sP.
//  kA (736 blocks, range-specialized):
//   [0,64)    P1: w = softmax_d(z*(a@Wqk + bqk)/sqrt192) (bk·q cancels),
//             attn_weights, ae = a@Wav + bav
//   [64,224)  U[h,d,k] = Wfv[d,:]·W1[h,0:128,k] ; dt==4: c0 = bfv·W1[h,0:128]+b1
//   [224,736) M_T[h][k2][k1] = (W2[h]@W1o[h])^T bf16 (16 blocks/h); c1 = b2@W1o+b1o
//  kB (1024 blocks, XCD-swizzled h, 16 b per block):
//   G[bi][k] = ae·W1[h,128:192,k] + c0      (LDS, two 32-reg passes)
//   P[bi][k] = sum_d w_d*relu(z_d*U + G)    (bf16 LDS)
//   effect   = relu(P@M + c1)·W2o + b2o     via mfma_f32_16x16x32_bf16

typedef __attribute__((ext_vector_type(8))) short bf16x8;
typedef __attribute__((ext_vector_type(4))) short bf16x4;
typedef __attribute__((ext_vector_type(4))) float f32x4;

__device__ __forceinline__ short f2bf(float x) {
  unsigned u = __float_as_uint(x);
  u += 0x7fffu + ((u >> 16) & 1u);          // round-to-nearest-even
  return (short)(u >> 16);
}

__global__ __launch_bounds__(256) void kA_prep(
    const float* __restrict__ feat, const float* __restrict__ act,
    const float* __restrict__ Wq, const float* __restrict__ bq,
    const float* __restrict__ Wk,
    const float* __restrict__ Wav, const float* __restrict__ bav,
    const float* __restrict__ Wfv, const float* __restrict__ bfv,
    const float* __restrict__ W1, const float* __restrict__ b1,
    const float* __restrict__ W2, const float* __restrict__ b2,
    const float* __restrict__ W1o, const float* __restrict__ b1o,
    float* __restrict__ ws_w, float* __restrict__ ws_ae,
    float* __restrict__ ws_U, float* __restrict__ ws_c0,
    unsigned short* __restrict__ ws_Mbf, float* __restrict__ ws_c1,
    float* __restrict__ out_aw) {
  __shared__ float sh[8448];                // 33 KB, aliased per range
  const int bx = blockIdx.x;
  const int t = threadIdx.x;

  if (bx < 64) {
    // ---------------- P1: softmax weights + attn_weights + ae (8 b per block)
    const int b0 = bx * 8;
    float* sWk = sh;                        // [192 c][32 d] transposed
    float* sA  = sh + 6144;                 // act [8][18]
    float* sQk = sh + 6320;                 // [19 j][32 d] (row 18 = bq row)
    float* sW  = sh + 6944;                 // [8][32]
#pragma unroll
    for (int i = 0; i < 24; ++i) {
      const int idx = i * 256 + t;          // idx = d*192 + c
      sWk[(idx % 192) * 32 + (idx / 192)] = Wk[idx];
    }
    if (t < 144) sA[t] = act[b0 * 18 + t];
    __syncthreads();
    for (int o = t; o < 608; o += 256) {    // Wqk[j][d]; j==18 -> bqk
      const int j = o >> 5, d = o & 31;
      const float* arow = (j < 18) ? (Wq + j * 192) : bq;
      float acc = 0.f;
      for (int c = 0; c < 192; ++c) acc += arow[c] * sWk[c * 32 + d];
      sQk[o] = acc;
    }
    __syncthreads();
    {
      const int bi = t >> 5, d = t & 31;
      float dot = sQk[18 * 32 + d];
#pragma unroll
      for (int j = 0; j < 18; ++j) dot += sA[bi * 18 + j] * sQk[j * 32 + d];
      const float z = feat[b0 * 32 + t];
      float sc = z * dot * 0.07216878364870322f;   // 1/sqrt(192)
      float mx = sc;
#pragma unroll
      for (int off = 16; off >= 1; off >>= 1) mx = fmaxf(mx, __shfl_xor(mx, off, 64));
      const float e = __expf(sc - mx);
      float s = e;
#pragma unroll
      for (int off = 16; off >= 1; off >>= 1) s += __shfl_xor(s, off, 64);
      const float w = e / s;
      ws_w[b0 * 32 + t] = w;
      sW[t] = w;
    }
#pragma unroll
    for (int o = t; o < 512; o += 256) {    // ae = a@Wav + bav
      const int bi = o >> 6, j = o & 63;
      float acc = bav[j];
#pragma unroll
      for (int jj = 0; jj < 18; ++jj) acc += sA[bi * 18 + jj] * Wav[jj * 64 + j];
      ws_ae[b0 * 64 + o] = acc;
    }
    __syncthreads();
#pragma unroll
    for (int i = 0; i < 32; ++i)
      out_aw[b0 * 1024 + i * 256 + t] = sW[(i >> 2) * 32 + (t & 31)];

  } else if (bx < 224) {
    // ---------------- U range: 5 blocks per h (dt<4: 8 d's; dt==4: c0)
    const int r = bx - 64;
    const int h = r / 5, dt = r % 5;
    float* sF = sh;                         // [8][128] Wfv tile (or bfv)
    if (dt < 4) {
#pragma unroll
      for (int i = 0; i < 4; ++i) sF[i * 256 + t] = Wfv[dt * 1024 + i * 256 + t];
    } else {
      if (t < 128) sF[t] = bfv[t];
    }
    __syncthreads();
    if (dt < 4) {
      float acc[8];
#pragma unroll
      for (int dd = 0; dd < 8; ++dd) acc[dd] = 0.f;
      for (int fc = 0; fc < 32; ++fc) {
        float w1v[4];
#pragma unroll
        for (int u = 0; u < 4; ++u) w1v[u] = W1[(h * 192 + fc * 4 + u) * 256 + t];
#pragma unroll
        for (int dd = 0; dd < 8; ++dd) {
          float4 f4 = *(const float4*)(sF + dd * 128 + fc * 4);
          acc[dd] += f4.x * w1v[0] + f4.y * w1v[1] + f4.z * w1v[2] + f4.w * w1v[3];
        }
      }
#pragma unroll
      for (int dd = 0; dd < 8; ++dd)
        ws_U[(h * 32 + dt * 8 + dd) * 256 + t] = acc[dd];
    } else {
      float acc = b1[h * 256 + t];
      for (int fc = 0; fc < 32; ++fc) {
        float w1v[4];
#pragma unroll
        for (int u = 0; u < 4; ++u) w1v[u] = W1[(h * 192 + fc * 4 + u) * 256 + t];
        float4 f4 = *(const float4*)(sF + fc * 4);
        acc += f4.x * w1v[0] + f4.y * w1v[1] + f4.z * w1v[2] + f4.w * w1v[3];
      }
      ws_c0[h * 256 + t] = acc;
    }

  } else {
    // ---------------- M range: 16 blocks/h, 16 k1-rows each
    const int r = bx - 224;
    const int h = r >> 4, kt = r & 15;
    float* s = sh;
#pragma unroll
    for (int i = 0; i < 12; ++i)
      s[i * 256 + t] = W2[h * 49152 + kt * 3072 + i * 256 + t];
    __syncthreads();
    float acc[16];
#pragma unroll
    for (int rr = 0; rr < 16; ++rr) acc[rr] = 0.f;
    float c1acc = 0.f;
    for (int vc = 0; vc < 48; ++vc) {
      float w1o[4], b2v[4];
#pragma unroll
      for (int u = 0; u < 4; ++u) {
        w1o[u] = W1o[(h * 192 + vc * 4 + u) * 256 + t];
        b2v[u] = b2[h * 192 + vc * 4 + u];
      }
      c1acc += b2v[0] * w1o[0] + b2v[1] * w1o[1] + b2v[2] * w1o[2] + b2v[3] * w1o[3];
#pragma unroll
      for (int rr = 0; rr < 16; ++rr) {
        float4 w2 = *(const float4*)(s + rr * 192 + vc * 4);
        acc[rr] += w2.x * w1o[0] + w2.y * w1o[1] + w2.z * w1o[2] + w2.w * w1o[3];
      }
    }
    if (kt == 0) ws_c1[h * 256 + t] = c1acc + b1o[h * 256 + t];
    __syncthreads();
#pragma unroll
    for (int rr = 0; rr < 16; ++rr) s[rr * 260 + t] = acc[rr];
    __syncthreads();
    const int k1l = t & 15, k2g = t >> 4;
#pragma unroll
    for (int it = 0; it < 16; ++it) {
      const int k2 = it * 16 + k2g;
      ws_Mbf[(h * 256 + k2) * 256 + kt * 16 + k1l] =
          (unsigned short)f2bf(s[k1l * 260 + k2]);
    }
  }
}

// ---------------------------------------------------------------- kB: G (LDS) -> P -> MFMA P@M -> effect
__global__ __launch_bounds__(256) void kB_main(
    const float* __restrict__ feat, const float* __restrict__ ws_w,
    const float* __restrict__ ws_U, const float* __restrict__ W1,
    const float* __restrict__ ws_ae, const float* __restrict__ ws_c0,
    const unsigned short* __restrict__ ws_Mbf, const float* __restrict__ ws_c1,
    const float* __restrict__ W2o, const float* __restrict__ b2o,
    float* __restrict__ out_eff) {
  const int bx = blockIdx.x;
  const int h = (bx & 7) * 4 + ((bx >> 3) & 3);   // XCD swizzle (bijective in bx&31)
  const int bt = bx >> 5;                   // 16 b per block
  const int b0 = bt * 16;
  const int t = threadIdx.x;

  __shared__ __align__(16) char smem[29440];
  short* sP   = (short*)smem;               // [16][264] bf16 : 8448 B
  float* sAe  = (float*)smem;               // [16][64], aliased with sP (G phase only)
  float* sG   = (float*)(smem + 8448);      // [16][260] : 16640 B
  float* sZ   = (float*)(smem + 25088);     // [16][32] feat
  float* sWw  = (float*)(smem + 27136);     // [16][32] softmax w
  float* sRed = (float*)(smem + 29184);     // [16][4]

  // ---- stage z, w, ae into LDS
  {
#pragma unroll
    for (int i = 0; i < 2; ++i) {
      sZ[i * 256 + t]  = feat[b0 * 32 + i * 256 + t];
      sWw[i * 256 + t] = ws_w[b0 * 32 + i * 256 + t];
    }
#pragma unroll
    for (int i = 0; i < 4; ++i) sAe[i * 256 + t] = ws_ae[b0 * 64 + i * 256 + t];
  }

  // ---- G in LDS: G[bi][k=t] = c0[k] + ae[bi]·W1[h,128:192,k], two 32-reg passes
  {
    const float c0v = ws_c0[h * 256 + t];
    float w1r[32];
#pragma unroll
    for (int j = 0; j < 32; ++j) w1r[j] = W1[(h * 192 + 128 + j) * 256 + t];
    __syncthreads();
#pragma unroll
    for (int bi = 0; bi < 16; ++bi) {
      float acc = c0v;
#pragma unroll
      for (int jc = 0; jc < 8; ++jc) {
        float4 a4 = *(const float4*)(sAe + bi * 64 + jc * 4);
        acc += a4.x * w1r[jc * 4 + 0] + a4.y * w1r[jc * 4 + 1]
             + a4.z * w1r[jc * 4 + 2] + a4.w * w1r[jc * 4 + 3];
      }
      sG[bi * 260 + t] = acc;
    }
#pragma unroll
    for (int j = 0; j < 32; ++j) w1r[j] = W1[(h * 192 + 160 + j) * 256 + t];
#pragma unroll
    for (int bi = 0; bi < 16; ++bi) {
      float acc = sG[bi * 260 + t];
#pragma unroll
      for (int jc = 0; jc < 8; ++jc) {
        float4 a4 = *(const float4*)(sAe + bi * 64 + 32 + jc * 4);
        acc += a4.x * w1r[jc * 4 + 0] + a4.y * w1r[jc * 4 + 1]
             + a4.z * w1r[jc * 4 + 2] + a4.w * w1r[jc * 4 + 3];
      }
      sG[bi * 260 + t] = acc;
    }
  }
  __syncthreads();   // sG, sZ, sWw ready; sAe dead (sP reuses its space)

  // ---- P: thread (bq = t>>6 -> rows bq*4..+3; kg = t&63 -> cols kg*4..+3)
  //      each U load reused across 4 rows in registers
  {
    const int bq = t >> 6, kg = t & 63;
    float g[4][4], acc[4][4];
#pragma unroll
    for (int r = 0; r < 4; ++r) {
      float4 g4 = *(const float4*)(sG + (bq * 4 + r) * 260 + kg * 4);
      g[r][0] = g4.x; g[r][1] = g4.y; g[r][2] = g4.z; g[r][3] = g4.w;
      acc[r][0] = 0.f; acc[r][1] = 0.f; acc[r][2] = 0.f; acc[r][3] = 0.f;
    }
    const float* Up = ws_U + h * 8192 + kg * 4;
    for (int dc = 0; dc < 8; ++dc) {
      float uc[4][4];
#pragma unroll
      for (int dd = 0; dd < 4; ++dd) {
        float4 u4 = *(const float4*)(Up + (dc * 4 + dd) * 256);
        uc[dd][0] = u4.x; uc[dd][1] = u4.y; uc[dd][2] = u4.z; uc[dd][3] = u4.w;
      }
      float zr[4][4], wr[4][4];
#pragma unroll
      for (int r = 0; r < 4; ++r) {
        float4 z4 = *(const float4*)(sZ + (bq * 4 + r) * 32 + dc * 4);
        float4 w4 = *(const float4*)(sWw + (bq * 4 + r) * 32 + dc * 4);
        zr[r][0] = z4.x; zr[r][1] = z4.y; zr[r][2] = z4.z; zr[r][3] = z4.w;
        wr[r][0] = w4.x; wr[r][1] = w4.y; wr[r][2] = w4.z; wr[r][3] = w4.w;
      }
#pragma unroll
      for (int dd = 0; dd < 4; ++dd) {
#pragma unroll
        for (int r = 0; r < 4; ++r) {
#pragma unroll
          for (int c = 0; c < 4; ++c)
            acc[r][c] += wr[r][dd] * fmaxf(zr[r][dd] * uc[dd][c] + g[r][c], 0.f);
        }
      }
    }
#pragma unroll
    for (int r = 0; r < 4; ++r) {
      bf16x4 p;
#pragma unroll
      for (int c = 0; c < 4; ++c) p[c] = f2bf(acc[r][c]);
      *(bf16x4*)(sP + (bq * 4 + r) * 264 + kg * 4) = p;
    }
  }
  __syncthreads();

  // ---- MFMA: D[16 b][64 k2 per wave] = P @ M ; epilogue
  {
    const int wv = t >> 6;
    const int lane = t & 63;
    const int quad = lane >> 4, l15 = lane & 15;

    f32x4 acc[4];
    const f32x4 zero = {0.f, 0.f, 0.f, 0.f};
#pragma unroll
    for (int nt = 0; nt < 4; ++nt) acc[nt] = zero;

    float c1r[4], w2r[4];
#pragma unroll
    for (int nt = 0; nt < 4; ++nt) {
      const int col = wv * 64 + nt * 16 + l15;
      c1r[nt] = ws_c1[h * 256 + col];
      w2r[nt] = W2o[h * 256 + col];
    }
    const unsigned short* Mp = ws_Mbf + (size_t)(h * 256 + wv * 64) * 256;

#pragma unroll
    for (int kc = 0; kc < 8; ++kc) {
      bf16x8 a0 = *(const bf16x8*)(sP + l15 * 264 + kc * 32 + quad * 8);
      bf16x8 bfr[4];
#pragma unroll
      for (int nt = 0; nt < 4; ++nt)
        bfr[nt] = *(const bf16x8*)(Mp + (nt * 16 + l15) * 256 + kc * 32 + quad * 8);
#pragma unroll
      for (int nt = 0; nt < 4; ++nt)
        acc[nt] = __builtin_amdgcn_mfma_f32_16x16x32_bf16(a0, bfr[nt], acc[nt], 0, 0, 0);
    }
#pragma unroll
    for (int r = 0; r < 4; ++r) {
      float s = fmaxf(acc[0][r] + c1r[0], 0.f) * w2r[0]
              + fmaxf(acc[1][r] + c1r[1], 0.f) * w2r[1]
              + fmaxf(acc[2][r] + c1r[2], 0.f) * w2r[2]
              + fmaxf(acc[3][r] + c1r[3], 0.f) * w2r[3];
      s += __shfl_xor(s, 1, 64);
      s += __shfl_xor(s, 2, 64);
      s += __shfl_xor(s, 4, 64);
      s += __shfl_xor(s, 8, 64);
      if (l15 == 0) sRed[(quad * 4 + r) * 4 + wv] = s;
    }
  }
  __syncthreads();
  if (t < 16) {
    float v = sRed[t * 4] + sRed[t * 4 + 1] + sRed[t * 4 + 2] + sRed[t * 4 + 3] + b2o[h];
    out_eff[(b0 + t) * 32 + h] = v;
  }
}

// ----------------------------------------------------------------
extern "C" void kernel_launch(void* const* d_in, const int* in_sizes, int n_in,
                              void* d_out, int out_size, void* d_ws, size_t ws_size,
                              hipStream_t stream) {
  const float* feat = (const float*)d_in[0];
  const float* act  = (const float*)d_in[1];
  const float* Wq   = (const float*)d_in[2];
  const float* bq   = (const float*)d_in[3];
  const float* Wk   = (const float*)d_in[4];
  // d_in[5] = bk: cancels in softmax
  const float* Wav  = (const float*)d_in[6];
  const float* bav  = (const float*)d_in[7];
  const float* Wfv  = (const float*)d_in[8];
  const float* bfv  = (const float*)d_in[9];
  const float* W1   = (const float*)d_in[10];
  const float* b1   = (const float*)d_in[11];
  const float* W2   = (const float*)d_in[12];
  const float* b2   = (const float*)d_in[13];
  const float* W1o  = (const float*)d_in[14];
  const float* b1o  = (const float*)d_in[15];
  const float* W2o  = (const float*)d_in[16];
  const float* b2o  = (const float*)d_in[17];
  float* out = (float*)d_out;               // [0,16384): effect; rest: attn_weights
  float* ws = (float*)d_ws;

  float* ws_w  = ws;                                        // 16384
  float* ws_ae = ws + 16384;                                // 32768
  float* ws_U  = ws + 49152;                                // 262144
  float* ws_c0 = ws + 311296;                               // 8192
  float* ws_c1 = ws + 319488;                               // 8192
  unsigned short* ws_Mbf = (unsigned short*)(ws + 327680);  // 2097152 shorts

  hipLaunchKernelGGL(kA_prep, dim3(736), dim3(256), 0, stream,
                     feat, act, Wq, bq, Wk, Wav, bav, Wfv, bfv, W1, b1,
                     W2, b2, W1o, b1o, ws_w, ws_ae, ws_U, ws_c0, ws_Mbf, ws_c1,
                     out + 16384);
  hipLaunchKernelGGL(kB_main, dim3(1024), dim3(256), 0, stream,
                     feat, ws_w, ws_U, W1, ws_ae, ws_c0, ws_Mbf, ws_c1,
                     W2o, b2o, out);
}